// Round 9
// baseline (251.649 us; speedup 1.0000x reference)
//
#include <hip/hip_runtime.h>
#include <cstdint>
#include <cstddef>

// ---- problem constants (B=1, S=2048, H=1024, NH=16, HD=64, NT=1024) ----
#define S_LEN 2048
#define H_DIM 1024
#define NTOK  1024
#define NHEAD 16
#define HDIM  64
#define NSPLIT 4

typedef __bf16 bf16;
typedef __bf16 bf16x8 __attribute__((ext_vector_type(8)));
typedef __bf16 bf16x4 __attribute__((ext_vector_type(4)));
typedef float  f32x4  __attribute__((ext_vector_type(4)));

static __device__ __forceinline__ f32x4 mfma16(bf16x8 a, bf16x8 b, f32x4 c) {
    return __builtin_amdgcn_mfma_f32_16x16x32_bf16(a, b, c, 0, 0, 0);
}

static __device__ __forceinline__ void async16(const void* gp, void* lp) {
    __builtin_amdgcn_global_load_lds(
        (const __attribute__((address_space(1))) void*)gp,
        (__attribute__((address_space(3))) void*)lp, 16, 0, 0);
}

// ---------------------------------------------------------------------------
// fp32 -> bf16 elementwise convert, 6 jobs of 1M elements each in one launch.
// ---------------------------------------------------------------------------
struct ConvArgs {
    const float* src[6];
    bf16* dst[6];
};
__global__ __launch_bounds__(256) void convert6(ConvArgs a) {
    const float* __restrict__ s = a.src[blockIdx.y];
    bf16* __restrict__ d = a.dst[blockIdx.y];
    size_t i = ((size_t)blockIdx.x * 256 + threadIdx.x) * 4;
    f32x4 v = *(const f32x4*)&s[i];
    bf16x4 o;
    o[0] = (bf16)v[0]; o[1] = (bf16)v[1]; o[2] = (bf16)v[2]; o[3] = (bf16)v[3];
    *(bf16x4*)&d[i] = o;
}

// ---------------------------------------------------------------------------
// fp32 1024x1024 -> transposed bf16 1024x1024 (4 matrices in one launch).
// ---------------------------------------------------------------------------
struct TcArgs {
    const float* src[4];
    bf16* dst[4];
};
__global__ void transpose_cvt(TcArgs a) {
    const float* __restrict__ in = a.src[blockIdx.z];
    bf16* __restrict__ out = a.dst[blockIdx.z];
    __shared__ float t[32][33];
    const int bx = blockIdx.x * 32, by = blockIdx.y * 32;
    const int x = threadIdx.x, y = threadIdx.y;
#pragma unroll
    for (int j = 0; j < 32; j += 8)
        t[y + j][x] = in[(size_t)(by + y + j) * 1024 + bx + x];
    __syncthreads();
#pragma unroll
    for (int j = 0; j < 32; j += 8)
        out[(size_t)(bx + y + j) * 1024 + by + x] = (bf16)t[x][y + j];
}

// ---------------------------------------------------------------------------
// Per-head V transpose with BAKED chunk swizzle:
//   VtG row (h*64+d), 64-col block: chunk c (8 elems) stored at c ^ (d&7).
// ---------------------------------------------------------------------------
__global__ __launch_bounds__(256) void vtrans_kernel(const bf16* __restrict__ V,
                                                     bf16* __restrict__ Vt) {
    const int k0 = blockIdx.x * 64, h = blockIdx.y;
    const int tid = threadIdx.x;
    __shared__ __align__(16) bf16 tile[64 * 64];
    const int kk = tid >> 3, d8 = (tid & 7) * 8;
#pragma unroll
    for (int p = 0; p < 2; ++p) {
        int k = kk + p * 32;
        bf16x8 v = *(const bf16x8*)&V[(size_t)(k0 + k) * H_DIM + h * 64 + d8];
#pragma unroll
        for (int e = 0; e < 8; ++e)
            tile[(d8 + e) * 64 + (k ^ ((d8 + e) & 56))] = v[e];
    }
    __syncthreads();
    const int d = tid >> 2;
#pragma unroll
    for (int c = 0; c < 2; ++c) {
        int k8 = ((tid & 3) * 2 + c) * 8;
        bf16x8 v = *(const bf16x8*)&tile[d * 64 + (k8 ^ (d & 56))];
        int pos = (((k8 >> 3) ^ (d & 7)) << 3);  // baked swizzle position
        *(bf16x8*)&Vt[((size_t)(h * 64 + d)) * 2048 + k0 + pos] = v;
    }
}

template <int MODE, typename OutT>
struct GemmArgs {
    const bf16* A[3];
    const bf16* B[3];
    OutT* C[3];
    const float* S[3];
};

// ---------------------------------------------------------------------------
// GEMM 128x128 (z-batched): C[2048,1024] = epi( A @ B^T ), K=1024.
// BK=64, double-buffered LDS via global_load_lds(16B), XOR seg swizzle,
// 4 waves x (64x64) = 4x4 subtiles. 32 MFMA per wave-iter vs 8 async16/thr.
// LDS 64 KB -> 2 blocks/CU; VGPR ~170 under (256,2) — no spill.
// ---------------------------------------------------------------------------
template <int MODE, typename OutT>
__global__ __launch_bounds__(256, 2) void gemm_bt128(GemmArgs<MODE, OutT> args) {
    constexpr int Kd = 1024, Nd = 1024, BK = 64;
    const bf16* __restrict__ A = args.A[blockIdx.z];
    const bf16* __restrict__ B = args.B[blockIdx.z];
    OutT* __restrict__ C = args.C[blockIdx.z];
    const float* __restrict__ S = args.S[blockIdx.z];

    __shared__ __align__(16) bf16 As[2][128 * BK];  // 2 x 16 KB
    __shared__ __align__(16) bf16 Bs[2][128 * BK];  // 2 x 16 KB

    const int tid = threadIdx.x;
    const int w = tid >> 6, lane = tid & 63, quad = lane >> 4, m16 = lane & 15;
    const int wm = (w >> 1) * 64, wn = (w & 1) * 64;
    const int bm = blockIdx.y * 128, bn = blockIdx.x * 128;

    const int srow = lane >> 3;
    const int sseg = ((lane & 7) ^ srow) * 8;

    auto stage = [&](int buf, int k0) {
        const bf16* Ab = A + (size_t)bm * Kd + k0;
        const bf16* Bb = B + (size_t)bn * Kd + k0;
#pragma unroll
        for (int c = 0; c < 4; ++c) {
            int chunk = w * 4 + c;
            async16(Ab + (size_t)(chunk * 8 + srow) * Kd + sseg,
                    &As[buf][chunk * 512]);
            async16(Bb + (size_t)(chunk * 8 + srow) * Kd + sseg,
                    &Bs[buf][chunk * 512]);
        }
    };

    f32x4 acc[4][4] = {};
    stage(0, 0);

    for (int k0 = 0; k0 < Kd; k0 += BK) {
        const int buf = (k0 >> 6) & 1;
        asm volatile("s_waitcnt vmcnt(0)" ::: "memory");
        __syncthreads();
        if (k0 + BK < Kd) stage(buf ^ 1, k0 + BK);

        bf16x8 a[2][4], b[2][4];
#pragma unroll
        for (int kc = 0; kc < 2; ++kc) {
#pragma unroll
            for (int i = 0; i < 4; ++i) {
                int row = wm + i * 16 + m16;
                a[kc][i] = *(const bf16x8*)
                    &As[buf][row * 64 + (((kc * 4 + quad) ^ (row & 7)) << 3)];
            }
#pragma unroll
            for (int j = 0; j < 4; ++j) {
                int row = wn + j * 16 + m16;
                b[kc][j] = *(const bf16x8*)
                    &Bs[buf][row * 64 + (((kc * 4 + quad) ^ (row & 7)) << 3)];
            }
        }
#pragma unroll
        for (int kc = 0; kc < 2; ++kc)
#pragma unroll
            for (int i = 0; i < 4; ++i)
#pragma unroll
                for (int j = 0; j < 4; ++j)
                    acc[i][j] = mfma16(a[kc][i], b[kc][j], acc[i][j]);
    }

#pragma unroll
    for (int i = 0; i < 4; ++i)
#pragma unroll
        for (int j = 0; j < 4; ++j)
#pragma unroll
            for (int r = 0; r < 4; ++r) {
                int row = bm + wm + i * 16 + quad * 4 + r;  // C/D: row=quad*4+reg
                int col = bn + wn + j * 16 + m16;           //      col=lane&15
                float v = acc[i][j][r];
                if (MODE == 1)
                    v = 0.5f * v * (1.0f + erff(v * 0.70710678118654752f));
                if (MODE == 2) v *= S[row];
                C[(size_t)row * Nd + col] = (OutT)v;
            }
}

// ---------------------------------------------------------------------------
// GEMM 128x64 (R3/R8-proven) — used for z=1 proj launches (256 blocks=1/CU).
// ---------------------------------------------------------------------------
template <int MODE, typename OutT>
__global__ __launch_bounds__(256, 3) void gemm_bt64(GemmArgs<MODE, OutT> args) {
    constexpr int Kd = 1024, Nd = 1024, BK = 64;
    const bf16* __restrict__ A = args.A[blockIdx.z];
    const bf16* __restrict__ B = args.B[blockIdx.z];
    OutT* __restrict__ C = args.C[blockIdx.z];
    const float* __restrict__ S = args.S[blockIdx.z];

    __shared__ __align__(16) bf16 As[2][128 * BK];
    __shared__ __align__(16) bf16 Bs[2][64 * BK];

    const int tid = threadIdx.x;
    const int w = tid >> 6, lane = tid & 63, quad = lane >> 4, m16 = lane & 15;
    const int wm = (w >> 1) * 64, wn = (w & 1) * 32;
    const int bm = blockIdx.y * 128, bn = blockIdx.x * 64;

    const int srow = lane >> 3;
    const int sseg = ((lane & 7) ^ srow) * 8;

    auto stage = [&](int buf, int k0) {
        const bf16* Ab = A + (size_t)bm * Kd + k0;
#pragma unroll
        for (int c = 0; c < 4; ++c) {
            int chunk = w * 4 + c;
            async16(Ab + (size_t)(chunk * 8 + srow) * Kd + sseg,
                    &As[buf][chunk * 512]);
        }
        const bf16* Bb = B + (size_t)bn * Kd + k0;
#pragma unroll
        for (int c = 0; c < 2; ++c) {
            int chunk = w * 2 + c;
            async16(Bb + (size_t)(chunk * 8 + srow) * Kd + sseg,
                    &Bs[buf][chunk * 512]);
        }
    };

    f32x4 acc[4][2] = {};
    stage(0, 0);

    for (int k0 = 0; k0 < Kd; k0 += BK) {
        const int buf = (k0 >> 6) & 1;
        asm volatile("s_waitcnt vmcnt(0)" ::: "memory");
        __syncthreads();
        if (k0 + BK < Kd) stage(buf ^ 1, k0 + BK);

        bf16x8 a[2][4], b[2][2];
#pragma unroll
        for (int kc = 0; kc < 2; ++kc) {
#pragma unroll
            for (int i = 0; i < 4; ++i) {
                int row = wm + i * 16 + m16;
                a[kc][i] = *(const bf16x8*)
                    &As[buf][row * 64 + (((kc * 4 + quad) ^ (row & 7)) << 3)];
            }
#pragma unroll
            for (int j = 0; j < 2; ++j) {
                int row = wn + j * 16 + m16;
                b[kc][j] = *(const bf16x8*)
                    &Bs[buf][row * 64 + (((kc * 4 + quad) ^ (row & 7)) << 3)];
            }
        }
#pragma unroll
        for (int kc = 0; kc < 2; ++kc)
#pragma unroll
            for (int i = 0; i < 4; ++i)
#pragma unroll
                for (int j = 0; j < 2; ++j)
                    acc[i][j] = mfma16(a[kc][i], b[kc][j], acc[i][j]);
    }

#pragma unroll
    for (int i = 0; i < 4; ++i)
#pragma unroll
        for (int j = 0; j < 2; ++j)
#pragma unroll
            for (int r = 0; r < 4; ++r) {
                int row = bm + wm + i * 16 + quad * 4 + r;
                int col = bn + wn + j * 16 + m16;
                float v = acc[i][j][r];
                if (MODE == 1)
                    v = 0.5f * v * (1.0f + erff(v * 0.70710678118654752f));
                if (MODE == 2) v *= S[row];
                C[(size_t)row * Nd + col] = (OutT)v;
            }
}

// ---------------------------------------------------------------------------
// Row scale only: S[row] = 32 / ||g_row||  (g left untouched).
// ---------------------------------------------------------------------------
struct ScaleArgs { const bf16* G[3]; float* S[3]; };
__global__ __launch_bounds__(256) void rowscale_kernel(ScaleArgs a) {
    __shared__ float wsum[4];
    const bf16* __restrict__ G = a.G[blockIdx.y];
    float* __restrict__ S = a.S[blockIdx.y];
    const int row = blockIdx.x, tid = threadIdx.x;
    bf16x4 g = *(const bf16x4*)&G[(size_t)row * 1024 + tid * 4];
    float f0 = (float)g[0], f1 = (float)g[1], f2 = (float)g[2], f3 = (float)g[3];
    float ss = f0 * f0 + f1 * f1 + f2 * f2 + f3 * f3;
#pragma unroll
    for (int sh = 1; sh < 64; sh <<= 1) ss += __shfl_xor(ss, sh);
    if ((tid & 63) == 0) wsum[tid >> 6] = ss;
    __syncthreads();
    if (tid == 0) {
        float total = wsum[0] + wsum[1] + wsum[2] + wsum[3];
        S[row] = 32.0f * rsqrtf(total);
    }
}

// ---------------------------------------------------------------------------
// Causal flash attention — S^T formulation (R8-proven, unchanged).
// ---------------------------------------------------------------------------
struct FlashArgs {
    const bf16* Q;
    const bf16* K;
    const bf16* VtG;
    bf16* op[NSPLIT];
    float* ml;
};

__global__ __launch_bounds__(256, 4) void flash_kernel(FlashArgs fa) {
    const int pr = blockIdx.x, h = blockIdx.y, s = blockIdx.z;
    const int tid = threadIdx.x;
    const int w = tid >> 6, lane = tid & 63, quad = lane >> 4, m16 = lane & 15;
    const int hOff = h * HDIM;

    __shared__ __align__(16) bf16 Vs[64 * 64];    // V^T tile (baked swizzle)
    __shared__ __align__(16) bf16 Pw[4][16][72];  // per-wave P: [qrow][kcol]

    const int vrow = tid >> 3, vchunk = (tid & 7) * 8;
    const bf16* VtH = fa.VtG + (size_t)hOff * 2048;
    bf16* __restrict__ Opart = fa.op[s];

#pragma unroll
    for (int ti = 0; ti < 2; ++ti) {
        const int qt = ti ? 31 - pr : pr;
        const int qRow = qt * 64 + w * 16 + m16;  // this lane's q-row
        bf16x8 bq[2];
        bq[0] = *(const bf16x8*)&fa.Q[(size_t)qRow * H_DIM + hOff + quad * 8];
        bq[1] = *(const bf16x8*)&fa.Q[(size_t)qRow * H_DIM + hOff + 32 + quad * 8];

        f32x4 oacc[4] = {};   // O^T C-layout: [d-subtile jd]; row=d, col=qrow
        float m_i = -1e30f, l_i = 0.0f;

        for (int kt = s; kt <= qt; kt += NSPLIT) {
            const int k0 = kt * 64;
            const bool diag = (kt == qt);
            __syncthreads();  // prior PV reads of Vs complete
#pragma unroll
            for (int p = 0; p < 2; ++p) {
                int d = vrow + p * 32;
                async16(VtH + (size_t)d * 2048 + k0 + vchunk,
                        &Vs[d * 64 + vchunk]);
            }
            // S^T = K Q^T
            f32x4 sacc[4] = {};
#pragma unroll
            for (int ks = 0; ks < 2; ++ks)
#pragma unroll
                for (int j = 0; j < 4; ++j) {
                    bf16x8 ak = *(const bf16x8*)
                        &fa.K[(size_t)(k0 + j * 16 + m16) * H_DIM + hOff +
                              ks * 32 + quad * 8];
                    sacc[j] = mfma16(ak, bq[ks], sacc[j]);
                }
            // online softmax: each lane owns q-row m16
            float sv[4][4];
            float mx = -1e30f;
#pragma unroll
            for (int j = 0; j < 4; ++j)
#pragma unroll
                for (int rr = 0; rr < 4; ++rr) {
                    float sc = sacc[j][rr] * 0.125f;
                    int kcol = k0 + j * 16 + quad * 4 + rr;
                    if (diag && kcol > qRow) sc = -1e30f;
                    sv[j][rr] = sc;
                    mx = fmaxf(mx, sc);
                }
            mx = fmaxf(mx, __shfl_xor(mx, 16));
            mx = fmaxf(mx, __shfl_xor(mx, 32));
            float mnew = fmaxf(m_i, mx);
            float alpha = __expf(m_i - mnew);
            m_i = mnew;
            float ls = 0.0f;
#pragma unroll
            for (int j = 0; j < 4; ++j) {
                bf16x4 pk;
#pragma unroll
                for (int rr = 0; rr < 4; ++rr) {
                    float p = __expf(sv[j][rr] - mnew);
                    ls += p;
                    pk[rr] = (bf16)p;
                }
                *(bf16x4*)&Pw[w][m16][j * 16 + quad * 4] = pk;
            }
            ls += __shfl_xor(ls, 16);
            ls += __shfl_xor(ls, 32);
            l_i = l_i * alpha + ls;
#pragma unroll
            for (int jd = 0; jd < 4; ++jd)
#pragma unroll
                for (int rr = 0; rr < 4; ++rr) oacc[jd][rr] *= alpha;
            asm volatile("s_waitcnt vmcnt(0)" ::: "memory");
            __syncthreads();  // V staged; Pw ordered by barrier's lgkm drain
            // O^T += V^T P^T
#pragma unroll
            for (int ks = 0; ks < 2; ++ks) {
                bf16x8 bp = *(const bf16x8*)&Pw[w][m16][ks * 32 + quad * 8];
#pragma unroll
                for (int jd = 0; jd < 4; ++jd) {
                    int d = jd * 16 + m16;
                    bf16x8 av = *(const bf16x8*)
                        &Vs[d * 64 + (((ks * 4 + quad) ^ (d & 7)) << 3)];
                    oacc[jd] = mfma16(av, bp, oacc[jd]);
                }
            }
        }
#pragma unroll
        for (int jd = 0; jd < 4; ++jd) {
            bf16x4 o4;
#pragma unroll
            for (int rr = 0; rr < 4; ++rr) o4[rr] = (bf16)oacc[jd][rr];
            *(bf16x4*)&Opart[(size_t)qRow * 1024 + hOff + jd * 16 + quad * 4] = o4;
        }
        if (quad == 0) {
            float* p = fa.ml + ((size_t)(s * 2048 + qRow) * 16 + h) * 2;
            p[0] = m_i;
            p[1] = l_i;
        }
    }
}

// ---------------------------------------------------------------------------
// Combine the split partials: one wave per (row, head), lane = d.
// ---------------------------------------------------------------------------
struct CombArgs {
    const bf16* op[NSPLIT];
    const float* ml;
    bf16* ctx;
};
__global__ __launch_bounds__(256) void combine_kernel(CombArgs ca) {
    const int unit = blockIdx.x * 4 + (threadIdx.x >> 6);
    const int row = unit >> 4, h = unit & 15;
    const int d = threadIdx.x & 63;
    float mv[NSPLIT], lv[NSPLIT], M = -1e30f;
#pragma unroll
    for (int s2 = 0; s2 < NSPLIT; ++s2) {
        const float* p = ca.ml + ((size_t)(s2 * 2048 + row) * 16 + h) * 2;
        mv[s2] = p[0];
        lv[s2] = p[1];
        M = fmaxf(M, mv[s2]);
    }
    float num = 0.0f, den = 0.0f;
#pragma unroll
    for (int s2 = 0; s2 < NSPLIT; ++s2) {
        float e = __expf(mv[s2] - M);
        den += lv[s2] * e;
        num += e * (float)ca.op[s2][(size_t)row * 1024 + h * 64 + d];
    }
    ca.ctx[(size_t)row * 1024 + h * 64 + d] = (bf16)(num / den);
}

// ---------------------------------------------------------------------------
// Orchestration. Inputs/outputs FLOAT32 per the reference.
// ws layout (40 MB, phase-aliased) — identical to R8.
// ---------------------------------------------------------------------------
extern "C" void kernel_launch(void* const* d_in, const int* in_sizes, int n_in,
                              void* d_out, int out_size, void* d_ws,
                              size_t ws_size, hipStream_t stream) {
    const float* x = (const float*)d_in[0];
    const float* keysF[4] = {(const float*)d_in[1], (const float*)d_in[3],
                             (const float*)d_in[5], (const float*)d_in[7]};
    const float* valsF[4] = {(const float*)d_in[2], (const float*)d_in[4],
                             (const float*)d_in[6], (const float*)d_in[8]};
    float* out = (float*)d_out;

    char* ws = (char*)d_ws;
    bf16* xb = (bf16*)(ws);
    bf16* g3[3];
    for (int i = 0; i < 3; ++i) g3[i] = (bf16*)(ws + (4ull << 20) + (size_t)i * (4ull << 20));
    bf16* kb16[4], *vT16[4];
    for (int i = 0; i < 4; ++i) {
        kb16[i] = (bf16*)(ws + (16ull << 20) + (size_t)i * (2ull << 20));
        vT16[i] = (bf16*)(ws + (24ull << 20) + (size_t)i * (2ull << 20));
    }
    bf16* qb    = (bf16*)(ws);
    bf16* kbuf  = (bf16*)(ws + (32ull << 20));
    bf16* vbuf  = (bf16*)(ws + (36ull << 20));
    float* mlbuf = (float*)(ws + (20ull << 20));
    float* Sbuf = (float*)(ws + (20ull << 20) + (1536ull << 10));
    bf16* VtG   = (bf16*)(ws + (24ull << 20));
    bf16* ctx   = (bf16*)(ws + (32ull << 20));
    bf16* projg = (bf16*)(ws + (4ull << 20));

    bf16* opart[NSPLIT];
    for (int i = 0; i < NSPLIT; ++i)
        opart[i] = (bf16*)(ws + (4ull << 20) + (size_t)i * (4ull << 20));

    // 1. convert x + 4 key matrices to bf16
    ConvArgs cva;
    cva.src[0] = x;             cva.dst[0] = xb;
    cva.src[1] = x + (1 << 20); cva.dst[1] = xb + (1 << 20);
    for (int i = 0; i < 4; ++i) { cva.src[2 + i] = keysF[i]; cva.dst[2 + i] = kb16[i]; }
    convert6<<<dim3(1024, 6), 256, 0, stream>>>(cva);

    // 2. convert + transpose the 4 val matrices
    TcArgs ta;
    for (int i = 0; i < 4; ++i) { ta.src[i] = valsF[i]; ta.dst[i] = vT16[i]; }
    transpose_cvt<<<dim3(32, 32, 4), dim3(32, 8), 0, stream>>>(ta);

    // 3. batched QKV: g = gelu(x @ key^T)   [128x128 tiles]
    GemmArgs<1, bf16> g1;
    for (int z = 0; z < 3; ++z) {
        g1.A[z] = xb; g1.B[z] = kb16[z]; g1.C[z] = g3[z]; g1.S[z] = nullptr;
    }
    gemm_bt128<1, bf16><<<dim3(8, 16, 3), 256, 0, stream>>>(g1);

    // 4. row scales only (g untouched)
    ScaleArgs sa;
    for (int z = 0; z < 3; ++z) { sa.G[z] = g3[z]; sa.S[z] = Sbuf + z * 2048; }
    rowscale_kernel<<<dim3(2048, 3), 256, 0, stream>>>(sa);

    // 5. batched: {q,k,v} = scale * (g @ val)   [128x128 tiles]
    GemmArgs<2, bf16> g2;
    bf16* qkv[3] = {qb, kbuf, vbuf};
    for (int z = 0; z < 3; ++z) {
        g2.A[z] = g3[z]; g2.B[z] = vT16[z]; g2.C[z] = qkv[z]; g2.S[z] = Sbuf + z * 2048;
    }
    gemm_bt128<2, bf16><<<dim3(8, 16, 3), 256, 0, stream>>>(g2);

    // 6. per-head V transpose (baked swizzle) for async flash staging
    vtrans_kernel<<<dim3(32, 16), 256, 0, stream>>>(vbuf, VtG);

    // 7. flash attention (S^T form, 1024 co-resident blocks, 4-way split)
    FlashArgs fla;
    fla.Q = qb; fla.K = kbuf; fla.VtG = VtG; fla.ml = mlbuf;
    for (int i = 0; i < NSPLIT; ++i) fla.op[i] = opart[i];
    flash_kernel<<<dim3(16, 16, NSPLIT), 256, 0, stream>>>(fla);

    // 8. combine split partials -> ctx
    CombArgs cba;
    for (int i = 0; i < NSPLIT; ++i) cba.op[i] = opart[i];
    cba.ml = mlbuf; cba.ctx = ctx;
    combine_kernel<<<dim3(8192), 256, 0, stream>>>(cba);

    // 9-11. output projection pattention  [128x64 tiles, 256 blocks = 1/CU]
    GemmArgs<1, bf16> p1;
    for (int z = 0; z < 3; ++z) {
        p1.A[z] = ctx; p1.B[z] = kb16[3]; p1.C[z] = projg; p1.S[z] = nullptr;
    }
    gemm_bt64<1, bf16><<<dim3(16, 16, 1), 256, 0, stream>>>(p1);

    ScaleArgs sp;
    for (int z = 0; z < 3; ++z) { sp.G[z] = projg; sp.S[z] = Sbuf; }
    rowscale_kernel<<<dim3(2048, 1), 256, 0, stream>>>(sp);

    GemmArgs<2, float> p2;
    for (int z = 0; z < 3; ++z) {
        p2.A[z] = projg; p2.B[z] = vT16[3]; p2.C[z] = out; p2.S[z] = Sbuf;
    }
    gemm_bt64<2, float><<<dim3(16, 16, 1), 256, 0, stream>>>(p2);
}

// Round 10
// 248.788 us; speedup vs baseline: 1.0115x; 1.0115x over previous
//
#include <hip/hip_runtime.h>
#include <cstdint>
#include <cstddef>

// ---- problem constants (B=1, S=2048, H=1024, NH=16, HD=64, NT=1024) ----
#define S_LEN 2048
#define H_DIM 1024
#define NTOK  1024
#define NHEAD 16
#define HDIM  64
#define NSPLIT 6

typedef __bf16 bf16;
typedef __bf16 bf16x8 __attribute__((ext_vector_type(8)));
typedef __bf16 bf16x4 __attribute__((ext_vector_type(4)));
typedef float  f32x4  __attribute__((ext_vector_type(4)));

static __device__ __forceinline__ f32x4 mfma16(bf16x8 a, bf16x8 b, f32x4 c) {
    return __builtin_amdgcn_mfma_f32_16x16x32_bf16(a, b, c, 0, 0, 0);
}

static __device__ __forceinline__ void async16(const void* gp, void* lp) {
    __builtin_amdgcn_global_load_lds(
        (const __attribute__((address_space(1))) void*)gp,
        (__attribute__((address_space(3))) void*)lp, 16, 0, 0);
}

// ---------------------------------------------------------------------------
// fp32 -> bf16 elementwise convert, 6 jobs of 1M elements each in one launch.
// ---------------------------------------------------------------------------
struct ConvArgs {
    const float* src[6];
    bf16* dst[6];
};
__global__ __launch_bounds__(256) void convert6(ConvArgs a) {
    const float* __restrict__ s = a.src[blockIdx.y];
    bf16* __restrict__ d = a.dst[blockIdx.y];
    size_t i = ((size_t)blockIdx.x * 256 + threadIdx.x) * 4;
    f32x4 v = *(const f32x4*)&s[i];
    bf16x4 o;
    o[0] = (bf16)v[0]; o[1] = (bf16)v[1]; o[2] = (bf16)v[2]; o[3] = (bf16)v[3];
    *(bf16x4*)&d[i] = o;
}

// ---------------------------------------------------------------------------
// fp32 1024x1024 -> transposed bf16 1024x1024 (4 matrices in one launch).
// ---------------------------------------------------------------------------
struct TcArgs {
    const float* src[4];
    bf16* dst[4];
};
__global__ void transpose_cvt(TcArgs a) {
    const float* __restrict__ in = a.src[blockIdx.z];
    bf16* __restrict__ out = a.dst[blockIdx.z];
    __shared__ float t[32][33];
    const int bx = blockIdx.x * 32, by = blockIdx.y * 32;
    const int x = threadIdx.x, y = threadIdx.y;
#pragma unroll
    for (int j = 0; j < 32; j += 8)
        t[y + j][x] = in[(size_t)(by + y + j) * 1024 + bx + x];
    __syncthreads();
#pragma unroll
    for (int j = 0; j < 32; j += 8)
        out[(size_t)(bx + y + j) * 1024 + by + x] = (bf16)t[x][y + j];
}

// ---------------------------------------------------------------------------
// Per-head V transpose with BAKED chunk swizzle:
//   VtG row (h*64+d), 64-col block: chunk c (8 elems) stored at c ^ (d&7).
// ---------------------------------------------------------------------------
__global__ __launch_bounds__(256) void vtrans_kernel(const bf16* __restrict__ V,
                                                     bf16* __restrict__ Vt) {
    const int k0 = blockIdx.x * 64, h = blockIdx.y;
    const int tid = threadIdx.x;
    __shared__ __align__(16) bf16 tile[64 * 64];
    const int kk = tid >> 3, d8 = (tid & 7) * 8;
#pragma unroll
    for (int p = 0; p < 2; ++p) {
        int k = kk + p * 32;
        bf16x8 v = *(const bf16x8*)&V[(size_t)(k0 + k) * H_DIM + h * 64 + d8];
#pragma unroll
        for (int e = 0; e < 8; ++e)
            tile[(d8 + e) * 64 + (k ^ ((d8 + e) & 56))] = v[e];
    }
    __syncthreads();
    const int d = tid >> 2;
#pragma unroll
    for (int c = 0; c < 2; ++c) {
        int k8 = ((tid & 3) * 2 + c) * 8;
        bf16x8 v = *(const bf16x8*)&tile[d * 64 + (k8 ^ (d & 56))];
        int pos = (((k8 >> 3) ^ (d & 7)) << 3);  // baked swizzle position
        *(bf16x8*)&Vt[((size_t)(h * 64 + d)) * 2048 + k0 + pos] = v;
    }
}

// ---------------------------------------------------------------------------
// GEMM (R8-proven): C[2048,1024] = epi( A @ B^T ), K=1024.
// 128x64 tile, BK=64, double-buffered LDS via global_load_lds(16B),
// global-side XOR seg swizzle -> conflict-free ds_read_b128 frags.
// MODE 0 plain, 1 exact-gelu, 2 row-scale. blockIdx.z batches QKV.
// 768 blocks (z=3) = 3/CU at __launch_bounds__(256,3).
// ---------------------------------------------------------------------------
template <int MODE, typename OutT>
struct GemmArgs {
    const bf16* A[3];
    const bf16* B[3];
    OutT* C[3];
    const float* S[3];
};

template <int MODE, typename OutT>
__global__ __launch_bounds__(256, 3) void gemm_bt(GemmArgs<MODE, OutT> args) {
    constexpr int Kd = 1024, Nd = 1024, BK = 64;
    const bf16* __restrict__ A = args.A[blockIdx.z];
    const bf16* __restrict__ B = args.B[blockIdx.z];
    OutT* __restrict__ C = args.C[blockIdx.z];
    const float* __restrict__ S = args.S[blockIdx.z];

    __shared__ __align__(16) bf16 As[2][128 * BK];
    __shared__ __align__(16) bf16 Bs[2][64 * BK];

    const int tid = threadIdx.x;
    const int w = tid >> 6, lane = tid & 63, quad = lane >> 4, m16 = lane & 15;
    const int wm = (w >> 1) * 64, wn = (w & 1) * 32;
    const int bm = blockIdx.y * 128, bn = blockIdx.x * 64;

    const int srow = lane >> 3;
    const int sseg = ((lane & 7) ^ srow) * 8;

    auto stage = [&](int buf, int k0) {
        const bf16* Ab = A + (size_t)bm * Kd + k0;
#pragma unroll
        for (int c = 0; c < 4; ++c) {
            int chunk = w * 4 + c;
            async16(Ab + (size_t)(chunk * 8 + srow) * Kd + sseg,
                    &As[buf][chunk * 512]);
        }
        const bf16* Bb = B + (size_t)bn * Kd + k0;
#pragma unroll
        for (int c = 0; c < 2; ++c) {
            int chunk = w * 2 + c;
            async16(Bb + (size_t)(chunk * 8 + srow) * Kd + sseg,
                    &Bs[buf][chunk * 512]);
        }
    };

    f32x4 acc[4][2] = {};
    stage(0, 0);

    for (int k0 = 0; k0 < Kd; k0 += BK) {
        const int buf = (k0 >> 6) & 1;
        asm volatile("s_waitcnt vmcnt(0)" ::: "memory");
        __syncthreads();
        if (k0 + BK < Kd) stage(buf ^ 1, k0 + BK);

        bf16x8 a[2][4], b[2][2];
#pragma unroll
        for (int kc = 0; kc < 2; ++kc) {
#pragma unroll
            for (int i = 0; i < 4; ++i) {
                int row = wm + i * 16 + m16;
                a[kc][i] = *(const bf16x8*)
                    &As[buf][row * 64 + (((kc * 4 + quad) ^ (row & 7)) << 3)];
            }
#pragma unroll
            for (int j = 0; j < 2; ++j) {
                int row = wn + j * 16 + m16;
                b[kc][j] = *(const bf16x8*)
                    &Bs[buf][row * 64 + (((kc * 4 + quad) ^ (row & 7)) << 3)];
            }
        }
#pragma unroll
        for (int kc = 0; kc < 2; ++kc)
#pragma unroll
            for (int i = 0; i < 4; ++i)
#pragma unroll
                for (int j = 0; j < 2; ++j)
                    acc[i][j] = mfma16(a[kc][i], b[kc][j], acc[i][j]);
    }

#pragma unroll
    for (int i = 0; i < 4; ++i)
#pragma unroll
        for (int j = 0; j < 2; ++j)
#pragma unroll
            for (int r = 0; r < 4; ++r) {
                int row = bm + wm + i * 16 + quad * 4 + r;
                int col = bn + wn + j * 16 + m16;
                float v = acc[i][j][r];
                if (MODE == 1)
                    v = 0.5f * v * (1.0f + erff(v * 0.70710678118654752f));
                if (MODE == 2) v *= S[row];
                C[(size_t)row * Nd + col] = (OutT)v;
            }
}

// ---------------------------------------------------------------------------
// Row scale only: S[row] = 32 / ||g_row||  (g left untouched).
// ---------------------------------------------------------------------------
struct ScaleArgs { const bf16* G[3]; float* S[3]; };
__global__ __launch_bounds__(256) void rowscale_kernel(ScaleArgs a) {
    __shared__ float wsum[4];
    const bf16* __restrict__ G = a.G[blockIdx.y];
    float* __restrict__ S = a.S[blockIdx.y];
    const int row = blockIdx.x, tid = threadIdx.x;
    bf16x4 g = *(const bf16x4*)&G[(size_t)row * 1024 + tid * 4];
    float f0 = (float)g[0], f1 = (float)g[1], f2 = (float)g[2], f3 = (float)g[3];
    float ss = f0 * f0 + f1 * f1 + f2 * f2 + f3 * f3;
#pragma unroll
    for (int sh = 1; sh < 64; sh <<= 1) ss += __shfl_xor(ss, sh);
    if ((tid & 63) == 0) wsum[tid >> 6] = ss;
    __syncthreads();
    if (tid == 0) {
        float total = wsum[0] + wsum[1] + wsum[2] + wsum[3];
        S[row] = 32.0f * rsqrtf(total);
    }
}

// ---------------------------------------------------------------------------
// Causal flash attention — S^T formulation (R8-proven body).
// VGPR=48 measured (R8/R9) -> fits the 6-waves/SIMD budget (<=85).
// Paired q-tiles {pr, 31-pr}, 6-way K-split: grid (16,16,6) = 1536 blocks
// = exactly 6/CU co-resident at __launch_bounds__(256,6), 24 waves/CU.
// LDS 17.4 KB x 6 = 104 KB/CU.
// ---------------------------------------------------------------------------
struct FlashArgs {
    const bf16* Q;
    const bf16* K;
    const bf16* VtG;
    bf16* op[NSPLIT];
    float* ml;
};

__global__ __launch_bounds__(256, 6) void flash_kernel(FlashArgs fa) {
    const int pr = blockIdx.x, h = blockIdx.y, s = blockIdx.z;
    const int tid = threadIdx.x;
    const int w = tid >> 6, lane = tid & 63, quad = lane >> 4, m16 = lane & 15;
    const int hOff = h * HDIM;

    __shared__ __align__(16) bf16 Vs[64 * 64];    // V^T tile (baked swizzle)
    __shared__ __align__(16) bf16 Pw[4][16][72];  // per-wave P: [qrow][kcol]

    const int vrow = tid >> 3, vchunk = (tid & 7) * 8;
    const bf16* VtH = fa.VtG + (size_t)hOff * 2048;
    bf16* __restrict__ Opart = fa.op[s];

#pragma unroll
    for (int ti = 0; ti < 2; ++ti) {
        const int qt = ti ? 31 - pr : pr;
        const int qRow = qt * 64 + w * 16 + m16;  // this lane's q-row
        bf16x8 bq[2];
        bq[0] = *(const bf16x8*)&fa.Q[(size_t)qRow * H_DIM + hOff + quad * 8];
        bq[1] = *(const bf16x8*)&fa.Q[(size_t)qRow * H_DIM + hOff + 32 + quad * 8];

        f32x4 oacc[4] = {};   // O^T C-layout: [d-subtile jd]; row=d, col=qrow
        float m_i = -1e30f, l_i = 0.0f;

        for (int kt = s; kt <= qt; kt += NSPLIT) {
            const int k0 = kt * 64;
            const bool diag = (kt == qt);
            __syncthreads();  // prior PV reads of Vs complete
#pragma unroll
            for (int p = 0; p < 2; ++p) {
                int d = vrow + p * 32;
                async16(VtH + (size_t)d * 2048 + k0 + vchunk,
                        &Vs[d * 64 + vchunk]);
            }
            // S^T = K Q^T
            f32x4 sacc[4] = {};
#pragma unroll
            for (int ks = 0; ks < 2; ++ks)
#pragma unroll
                for (int j = 0; j < 4; ++j) {
                    bf16x8 ak = *(const bf16x8*)
                        &fa.K[(size_t)(k0 + j * 16 + m16) * H_DIM + hOff +
                              ks * 32 + quad * 8];
                    sacc[j] = mfma16(ak, bq[ks], sacc[j]);
                }
            // online softmax: each lane owns q-row m16
            float sv[4][4];
            float mx = -1e30f;
#pragma unroll
            for (int j = 0; j < 4; ++j)
#pragma unroll
                for (int rr = 0; rr < 4; ++rr) {
                    float sc = sacc[j][rr] * 0.125f;
                    int kcol = k0 + j * 16 + quad * 4 + rr;
                    if (diag && kcol > qRow) sc = -1e30f;
                    sv[j][rr] = sc;
                    mx = fmaxf(mx, sc);
                }
            mx = fmaxf(mx, __shfl_xor(mx, 16));
            mx = fmaxf(mx, __shfl_xor(mx, 32));
            float mnew = fmaxf(m_i, mx);
            float alpha = __expf(m_i - mnew);
            m_i = mnew;
            float ls = 0.0f;
#pragma unroll
            for (int j = 0; j < 4; ++j) {
                bf16x4 pk;
#pragma unroll
                for (int rr = 0; rr < 4; ++rr) {
                    float p = __expf(sv[j][rr] - mnew);
                    ls += p;
                    pk[rr] = (bf16)p;
                }
                *(bf16x4*)&Pw[w][m16][j * 16 + quad * 4] = pk;
            }
            ls += __shfl_xor(ls, 16);
            ls += __shfl_xor(ls, 32);
            l_i = l_i * alpha + ls;
#pragma unroll
            for (int jd = 0; jd < 4; ++jd)
#pragma unroll
                for (int rr = 0; rr < 4; ++rr) oacc[jd][rr] *= alpha;
            asm volatile("s_waitcnt vmcnt(0)" ::: "memory");
            __syncthreads();  // V staged; Pw ordered by barrier's lgkm drain
            // O^T += V^T P^T
#pragma unroll
            for (int ks = 0; ks < 2; ++ks) {
                bf16x8 bp = *(const bf16x8*)&Pw[w][m16][ks * 32 + quad * 8];
#pragma unroll
                for (int jd = 0; jd < 4; ++jd) {
                    int d = jd * 16 + m16;
                    bf16x8 av = *(const bf16x8*)
                        &Vs[d * 64 + (((ks * 4 + quad) ^ (d & 7)) << 3)];
                    oacc[jd] = mfma16(av, bp, oacc[jd]);
                }
            }
        }
#pragma unroll
        for (int jd = 0; jd < 4; ++jd) {
            bf16x4 o4;
#pragma unroll
            for (int rr = 0; rr < 4; ++rr) o4[rr] = (bf16)oacc[jd][rr];
            *(bf16x4*)&Opart[(size_t)qRow * 1024 + hOff + jd * 16 + quad * 4] = o4;
        }
        if (quad == 0) {
            float* p = fa.ml + ((size_t)(s * 2048 + qRow) * 16 + h) * 2;
            p[0] = m_i;
            p[1] = l_i;
        }
    }
}

// ---------------------------------------------------------------------------
// Combine the split partials: one wave per (row, head), lane = d.
// ---------------------------------------------------------------------------
struct CombArgs {
    const bf16* op[NSPLIT];
    const float* ml;
    bf16* ctx;
};
__global__ __launch_bounds__(256) void combine_kernel(CombArgs ca) {
    const int unit = blockIdx.x * 4 + (threadIdx.x >> 6);
    const int row = unit >> 4, h = unit & 15;
    const int d = threadIdx.x & 63;
    float mv[NSPLIT], lv[NSPLIT], M = -1e30f;
#pragma unroll
    for (int s2 = 0; s2 < NSPLIT; ++s2) {
        const float* p = ca.ml + ((size_t)(s2 * 2048 + row) * 16 + h) * 2;
        mv[s2] = p[0];
        lv[s2] = p[1];
        M = fmaxf(M, mv[s2]);
    }
    float num = 0.0f, den = 0.0f;
#pragma unroll
    for (int s2 = 0; s2 < NSPLIT; ++s2) {
        float e = __expf(mv[s2] - M);
        den += lv[s2] * e;
        num += e * (float)ca.op[s2][(size_t)row * 1024 + h * 64 + d];
    }
    ca.ctx[(size_t)row * 1024 + h * 64 + d] = (bf16)(num / den);
}

// ---------------------------------------------------------------------------
// Orchestration. Inputs/outputs FLOAT32 per the reference.
// ws layout (40 MB, phase-aliased):
//   0..4M    xb -> qb                16..24M  kb16[0..3] (kb16[3]=proj key, 22-24M)
//   4..16M   g3[0..2] -> Opart s0-2  24..32M  vT16[0..3] (vT16[3]=proj val, 30-32M)
//   16..20M  kb16[0,1] (dead) -> Opart s3
//   20..22M  kb16[2]   (dead) -> ml (1.5M) + Sbuf (24K @ +1.5M)
//   24..28M  vT16[0,1] (dead) -> VtG (swizzled per-head V^T)
//   32..36M  kbuf -> ctx             36..40M  vbuf
//   d_out (8M fp32, dead until final gemm) -> Opart s4 (0..4M), s5 (4..8M)
//   projg aliases 4..8M after combine.
// ---------------------------------------------------------------------------
extern "C" void kernel_launch(void* const* d_in, const int* in_sizes, int n_in,
                              void* d_out, int out_size, void* d_ws,
                              size_t ws_size, hipStream_t stream) {
    const float* x = (const float*)d_in[0];
    const float* keysF[4] = {(const float*)d_in[1], (const float*)d_in[3],
                             (const float*)d_in[5], (const float*)d_in[7]};
    const float* valsF[4] = {(const float*)d_in[2], (const float*)d_in[4],
                             (const float*)d_in[6], (const float*)d_in[8]};
    float* out = (float*)d_out;

    char* ws = (char*)d_ws;
    bf16* xb = (bf16*)(ws);
    bf16* g3[3];
    for (int i = 0; i < 3; ++i) g3[i] = (bf16*)(ws + (4ull << 20) + (size_t)i * (4ull << 20));
    bf16* kb16[4], *vT16[4];
    for (int i = 0; i < 4; ++i) {
        kb16[i] = (bf16*)(ws + (16ull << 20) + (size_t)i * (2ull << 20));
        vT16[i] = (bf16*)(ws + (24ull << 20) + (size_t)i * (2ull << 20));
    }
    bf16* qb    = (bf16*)(ws);
    bf16* kbuf  = (bf16*)(ws + (32ull << 20));
    bf16* vbuf  = (bf16*)(ws + (36ull << 20));
    float* mlbuf = (float*)(ws + (20ull << 20));
    float* Sbuf = (float*)(ws + (20ull << 20) + (1536ull << 10));
    bf16* VtG   = (bf16*)(ws + (24ull << 20));
    bf16* ctx   = (bf16*)(ws + (32ull << 20));
    bf16* projg = (bf16*)(ws + (4ull << 20));

    bf16* opart[NSPLIT];
    for (int i = 0; i < 4; ++i)
        opart[i] = (bf16*)(ws + (4ull << 20) + (size_t)i * (4ull << 20));
    opart[4] = (bf16*)d_out;                    // d_out dead until proj gemm2
    opart[5] = (bf16*)d_out + (2ull << 20);

    // 1. convert x + 4 key matrices to bf16
    ConvArgs cva;
    cva.src[0] = x;             cva.dst[0] = xb;
    cva.src[1] = x + (1 << 20); cva.dst[1] = xb + (1 << 20);
    for (int i = 0; i < 4; ++i) { cva.src[2 + i] = keysF[i]; cva.dst[2 + i] = kb16[i]; }
    convert6<<<dim3(1024, 6), 256, 0, stream>>>(cva);

    // 2. convert + transpose the 4 val matrices
    TcArgs ta;
    for (int i = 0; i < 4; ++i) { ta.src[i] = valsF[i]; ta.dst[i] = vT16[i]; }
    transpose_cvt<<<dim3(32, 32, 4), dim3(32, 8), 0, stream>>>(ta);

    // 3. batched QKV: g = gelu(x @ key^T)
    GemmArgs<1, bf16> g1;
    for (int z = 0; z < 3; ++z) {
        g1.A[z] = xb; g1.B[z] = kb16[z]; g1.C[z] = g3[z]; g1.S[z] = nullptr;
    }
    gemm_bt<1, bf16><<<dim3(16, 16, 3), 256, 0, stream>>>(g1);

    // 4. row scales only (g untouched)
    ScaleArgs sa;
    for (int z = 0; z < 3; ++z) { sa.G[z] = g3[z]; sa.S[z] = Sbuf + z * 2048; }
    rowscale_kernel<<<dim3(2048, 3), 256, 0, stream>>>(sa);

    // 5. batched: {q,k,v} = scale * (g @ val)
    GemmArgs<2, bf16> g2;
    bf16* qkv[3] = {qb, kbuf, vbuf};
    for (int z = 0; z < 3; ++z) {
        g2.A[z] = g3[z]; g2.B[z] = vT16[z]; g2.C[z] = qkv[z]; g2.S[z] = Sbuf + z * 2048;
    }
    gemm_bt<2, bf16><<<dim3(16, 16, 3), 256, 0, stream>>>(g2);

    // 6. per-head V transpose (baked swizzle) for async flash staging
    vtrans_kernel<<<dim3(32, 16), 256, 0, stream>>>(vbuf, VtG);

    // 7. flash attention (S^T form, 1536 co-resident blocks, 6-way split)
    FlashArgs fla;
    fla.Q = qb; fla.K = kbuf; fla.VtG = VtG; fla.ml = mlbuf;
    for (int i = 0; i < NSPLIT; ++i) fla.op[i] = opart[i];
    flash_kernel<<<dim3(16, 16, NSPLIT), 256, 0, stream>>>(fla);

    // 8. combine split partials -> ctx
    CombArgs cba;
    for (int i = 0; i < NSPLIT; ++i) cba.op[i] = opart[i];
    cba.ml = mlbuf; cba.ctx = ctx;
    combine_kernel<<<dim3(8192), 256, 0, stream>>>(cba);

    // 9-11. output projection pattention
    GemmArgs<1, bf16> p1;
    for (int z = 0; z < 3; ++z) {
        p1.A[z] = ctx; p1.B[z] = kb16[3]; p1.C[z] = projg; p1.S[z] = nullptr;
    }
    gemm_bt<1, bf16><<<dim3(16, 16, 1), 256, 0, stream>>>(p1);

    ScaleArgs sp;
    for (int z = 0; z < 3; ++z) { sp.G[z] = projg; sp.S[z] = Sbuf; }
    rowscale_kernel<<<dim3(2048, 1), 256, 0, stream>>>(sp);

    GemmArgs<2, float> p2;
    for (int z = 0; z < 3; ++z) {
        p2.A[z] = projg; p2.B[z] = vT16[3]; p2.C[z] = out; p2.S[z] = Sbuf;
    }
    gemm_bt<2, float><<<dim3(16, 16, 1), 256, 0, stream>>>(p2);
}

// Round 11
// 237.304 us; speedup vs baseline: 1.0605x; 1.0484x over previous
//
#include <hip/hip_runtime.h>
#include <cstdint>
#include <cstddef>

// ---- problem constants (B=1, S=2048, H=1024, NH=16, HD=64, NT=1024) ----
#define S_LEN 2048
#define H_DIM 1024
#define NTOK  1024
#define NHEAD 16
#define HDIM  64
#define NSPLIT 4

typedef __bf16 bf16;
typedef __bf16 bf16x8 __attribute__((ext_vector_type(8)));
typedef __bf16 bf16x4 __attribute__((ext_vector_type(4)));
typedef float  f32x4  __attribute__((ext_vector_type(4)));

static __device__ __forceinline__ f32x4 mfma16(bf16x8 a, bf16x8 b, f32x4 c) {
    return __builtin_amdgcn_mfma_f32_16x16x32_bf16(a, b, c, 0, 0, 0);
}

static __device__ __forceinline__ void async16(const void* gp, void* lp) {
    __builtin_amdgcn_global_load_lds(
        (const __attribute__((address_space(1))) void*)gp,
        (__attribute__((address_space(3))) void*)lp, 16, 0, 0);
}

// ---------------------------------------------------------------------------
// fp32 -> bf16 elementwise convert, 6 jobs of 1M elements each in one launch.
// ---------------------------------------------------------------------------
struct ConvArgs {
    const float* src[6];
    bf16* dst[6];
};
__global__ __launch_bounds__(256) void convert6(ConvArgs a) {
    const float* __restrict__ s = a.src[blockIdx.y];
    bf16* __restrict__ d = a.dst[blockIdx.y];
    size_t i = ((size_t)blockIdx.x * 256 + threadIdx.x) * 4;
    f32x4 v = *(const f32x4*)&s[i];
    bf16x4 o;
    o[0] = (bf16)v[0]; o[1] = (bf16)v[1]; o[2] = (bf16)v[2]; o[3] = (bf16)v[3];
    *(bf16x4*)&d[i] = o;
}

// ---------------------------------------------------------------------------
// fp32 1024x1024 -> transposed bf16 1024x1024 (4 matrices in one launch).
// ---------------------------------------------------------------------------
struct TcArgs {
    const float* src[4];
    bf16* dst[4];
};
__global__ void transpose_cvt(TcArgs a) {
    const float* __restrict__ in = a.src[blockIdx.z];
    bf16* __restrict__ out = a.dst[blockIdx.z];
    __shared__ float t[32][33];
    const int bx = blockIdx.x * 32, by = blockIdx.y * 32;
    const int x = threadIdx.x, y = threadIdx.y;
#pragma unroll
    for (int j = 0; j < 32; j += 8)
        t[y + j][x] = in[(size_t)(by + y + j) * 1024 + bx + x];
    __syncthreads();
#pragma unroll
    for (int j = 0; j < 32; j += 8)
        out[(size_t)(bx + y + j) * 1024 + by + x] = (bf16)t[x][y + j];
}

// ---------------------------------------------------------------------------
// GEMM args. Ct[z] != nullptr (MODE 2 only) => write V^T-layout (VtG) with
// baked chunk swizzle instead of row-major C.
// ---------------------------------------------------------------------------
template <int MODE, typename OutT>
struct GemmArgs {
    const bf16* A[3];
    const bf16* B[3];
    OutT* C[3];
    const float* S[3];
    bf16* Ct[3];
};

// ---------------------------------------------------------------------------
// GEMM (R8-proven): 128x64 tile, BK=64, dbuf async16 staging, XOR swizzle.
// 4 waves x (64x32). 768 blocks (z=3) = 3/CU at (256,3).
// ---------------------------------------------------------------------------
template <int MODE, typename OutT>
__global__ __launch_bounds__(256, 3) void gemm_bt(GemmArgs<MODE, OutT> args) {
    constexpr int Kd = 1024, Nd = 1024, BK = 64;
    const bf16* __restrict__ A = args.A[blockIdx.z];
    const bf16* __restrict__ B = args.B[blockIdx.z];
    OutT* __restrict__ C = args.C[blockIdx.z];
    const float* __restrict__ S = args.S[blockIdx.z];
    bf16* __restrict__ Ct = args.Ct[blockIdx.z];

    __shared__ __align__(16) bf16 As[2][128 * BK];
    __shared__ __align__(16) bf16 Bs[2][64 * BK];

    const int tid = threadIdx.x;
    const int w = tid >> 6, lane = tid & 63, quad = lane >> 4, m16 = lane & 15;
    const int wm = (w >> 1) * 64, wn = (w & 1) * 32;
    const int bm = blockIdx.y * 128, bn = blockIdx.x * 64;

    const int srow = lane >> 3;
    const int sseg = ((lane & 7) ^ srow) * 8;

    auto stage = [&](int buf, int k0) {
        const bf16* Ab = A + (size_t)bm * Kd + k0;
#pragma unroll
        for (int c = 0; c < 4; ++c) {
            int chunk = w * 4 + c;
            async16(Ab + (size_t)(chunk * 8 + srow) * Kd + sseg,
                    &As[buf][chunk * 512]);
        }
        const bf16* Bb = B + (size_t)bn * Kd + k0;
#pragma unroll
        for (int c = 0; c < 2; ++c) {
            int chunk = w * 2 + c;
            async16(Bb + (size_t)(chunk * 8 + srow) * Kd + sseg,
                    &Bs[buf][chunk * 512]);
        }
    };

    f32x4 acc[4][2] = {};
    stage(0, 0);

    for (int k0 = 0; k0 < Kd; k0 += BK) {
        const int buf = (k0 >> 6) & 1;
        asm volatile("s_waitcnt vmcnt(0)" ::: "memory");
        __syncthreads();
        if (k0 + BK < Kd) stage(buf ^ 1, k0 + BK);

        bf16x8 a[2][4], b[2][2];
#pragma unroll
        for (int kc = 0; kc < 2; ++kc) {
#pragma unroll
            for (int i = 0; i < 4; ++i) {
                int row = wm + i * 16 + m16;
                a[kc][i] = *(const bf16x8*)
                    &As[buf][row * 64 + (((kc * 4 + quad) ^ (row & 7)) << 3)];
            }
#pragma unroll
            for (int j = 0; j < 2; ++j) {
                int row = wn + j * 16 + m16;
                b[kc][j] = *(const bf16x8*)
                    &Bs[buf][row * 64 + (((kc * 4 + quad) ^ (row & 7)) << 3)];
            }
        }
#pragma unroll
        for (int kc = 0; kc < 2; ++kc)
#pragma unroll
            for (int i = 0; i < 4; ++i)
#pragma unroll
                for (int j = 0; j < 2; ++j)
                    acc[i][j] = mfma16(a[kc][i], b[kc][j], acc[i][j]);
    }

    if (MODE == 2 && Ct != nullptr) {
        // transposed + swizzle-baked VtG write: Ct[col][k] layout, chunk
        // (k&63)>>3 stored at (chunk ^ (col&7)); 4 contiguous k per lane.
#pragma unroll
        for (int i = 0; i < 4; ++i)
#pragma unroll
            for (int j = 0; j < 2; ++j) {
                int k = bm + wm + i * 16 + quad * 4;  // base of 4 contig k
                int col = bn + wn + j * 16 + m16;     // d-index (h*64+d)
                bf16x4 o4;
#pragma unroll
                for (int r = 0; r < 4; ++r)
                    o4[r] = (bf16)(acc[i][j][r] * S[k + r]);
                int kb = k >> 6, c = (k >> 3) & 7, off = k & 7;
                int pos = ((c ^ (col & 7)) << 3) + off;
                *(bf16x4*)&Ct[(size_t)col * 2048 + kb * 64 + pos] = o4;
            }
        return;
    }

#pragma unroll
    for (int i = 0; i < 4; ++i)
#pragma unroll
        for (int j = 0; j < 2; ++j)
#pragma unroll
            for (int r = 0; r < 4; ++r) {
                int row = bm + wm + i * 16 + quad * 4 + r;
                int col = bn + wn + j * 16 + m16;
                float v = acc[i][j][r];
                if (MODE == 1)
                    v = 0.5f * v * (1.0f + erff(v * 0.70710678118654752f));
                if (MODE == 2) v *= S[row];
                C[(size_t)row * Nd + col] = (OutT)v;
            }
}

// ---------------------------------------------------------------------------
// GEMM 512-thread variant for z=1 proj launches: 128x64 tile, 8 waves of
// 32x32 -> 8 waves/CU at 1 block/CU (vs 4) for latency hiding.
// ---------------------------------------------------------------------------
template <int MODE, typename OutT>
__global__ __launch_bounds__(512) void gemm_bt512(GemmArgs<MODE, OutT> args) {
    constexpr int Kd = 1024, Nd = 1024, BK = 64;
    const bf16* __restrict__ A = args.A[blockIdx.z];
    const bf16* __restrict__ B = args.B[blockIdx.z];
    OutT* __restrict__ C = args.C[blockIdx.z];
    const float* __restrict__ S = args.S[blockIdx.z];

    __shared__ __align__(16) bf16 As[2][128 * BK];
    __shared__ __align__(16) bf16 Bs[2][64 * BK];

    const int tid = threadIdx.x;
    const int w = tid >> 6, lane = tid & 63, quad = lane >> 4, m16 = lane & 15;
    const int wm = (w >> 1) * 32, wn = (w & 1) * 32;
    const int bm = blockIdx.y * 128, bn = blockIdx.x * 64;

    const int srow = lane >> 3;
    const int sseg = ((lane & 7) ^ srow) * 8;

    auto stage = [&](int buf, int k0) {
        const bf16* Ab = A + (size_t)bm * Kd + k0;
#pragma unroll
        for (int c = 0; c < 2; ++c) {
            int chunk = w * 2 + c;
            async16(Ab + (size_t)(chunk * 8 + srow) * Kd + sseg,
                    &As[buf][chunk * 512]);
        }
        const bf16* Bb = B + (size_t)bn * Kd + k0;
        {
            int chunk = w;
            async16(Bb + (size_t)(chunk * 8 + srow) * Kd + sseg,
                    &Bs[buf][chunk * 512]);
        }
    };

    f32x4 acc[2][2] = {};
    stage(0, 0);

    for (int k0 = 0; k0 < Kd; k0 += BK) {
        const int buf = (k0 >> 6) & 1;
        asm volatile("s_waitcnt vmcnt(0)" ::: "memory");
        __syncthreads();
        if (k0 + BK < Kd) stage(buf ^ 1, k0 + BK);

        bf16x8 a[2][2], b[2][2];
#pragma unroll
        for (int kc = 0; kc < 2; ++kc) {
#pragma unroll
            for (int i = 0; i < 2; ++i) {
                int row = wm + i * 16 + m16;
                a[kc][i] = *(const bf16x8*)
                    &As[buf][row * 64 + (((kc * 4 + quad) ^ (row & 7)) << 3)];
            }
#pragma unroll
            for (int j = 0; j < 2; ++j) {
                int row = wn + j * 16 + m16;
                b[kc][j] = *(const bf16x8*)
                    &Bs[buf][row * 64 + (((kc * 4 + quad) ^ (row & 7)) << 3)];
            }
        }
#pragma unroll
        for (int kc = 0; kc < 2; ++kc)
#pragma unroll
            for (int i = 0; i < 2; ++i)
#pragma unroll
                for (int j = 0; j < 2; ++j)
                    acc[i][j] = mfma16(a[kc][i], b[kc][j], acc[i][j]);
    }

#pragma unroll
    for (int i = 0; i < 2; ++i)
#pragma unroll
        for (int j = 0; j < 2; ++j)
#pragma unroll
            for (int r = 0; r < 4; ++r) {
                int row = bm + wm + i * 16 + quad * 4 + r;
                int col = bn + wn + j * 16 + m16;
                float v = acc[i][j][r];
                if (MODE == 1)
                    v = 0.5f * v * (1.0f + erff(v * 0.70710678118654752f));
                if (MODE == 2) v *= S[row];
                C[(size_t)row * Nd + col] = (OutT)v;
            }
}

// ---------------------------------------------------------------------------
// Row scale only: S[row] = 32 / ||g_row||  (g left untouched).
// ---------------------------------------------------------------------------
struct ScaleArgs { const bf16* G[3]; float* S[3]; };
__global__ __launch_bounds__(256) void rowscale_kernel(ScaleArgs a) {
    __shared__ float wsum[4];
    const bf16* __restrict__ G = a.G[blockIdx.y];
    float* __restrict__ S = a.S[blockIdx.y];
    const int row = blockIdx.x, tid = threadIdx.x;
    bf16x4 g = *(const bf16x4*)&G[(size_t)row * 1024 + tid * 4];
    float f0 = (float)g[0], f1 = (float)g[1], f2 = (float)g[2], f3 = (float)g[3];
    float ss = f0 * f0 + f1 * f1 + f2 * f2 + f3 * f3;
#pragma unroll
    for (int sh = 1; sh < 64; sh <<= 1) ss += __shfl_xor(ss, sh);
    if ((tid & 63) == 0) wsum[tid >> 6] = ss;
    __syncthreads();
    if (tid == 0) {
        float total = wsum[0] + wsum[1] + wsum[2] + wsum[3];
        S[row] = 32.0f * rsqrtf(total);
    }
}

// ---------------------------------------------------------------------------
// Causal flash attention — S^T formulation (R8 body) + XCD-aware decode:
// 1-D grid of 1024; xcd = bid&7 (dispatch round-robin heuristic) owns 2
// heads -> per-XCD working set Q+K+Vt ~1.5 MB fits 4 MB L2, so critical-path
// K loads become L2 hits. Paired q-tiles, NSPLIT=4, (256,4): no spill.
// ---------------------------------------------------------------------------
struct FlashArgs {
    const bf16* Q;
    const bf16* K;
    const bf16* VtG;
    bf16* op[NSPLIT];
    float* ml;
};

__global__ __launch_bounds__(256, 4) void flash_kernel(FlashArgs fa) {
    const int bid = blockIdx.x;
    const int idx = bid >> 3;
    const int h = (bid & 7) * 2 + (idx & 1);
    const int pr = (idx >> 1) & 15;
    const int s = idx >> 5;
    const int tid = threadIdx.x;
    const int w = tid >> 6, lane = tid & 63, quad = lane >> 4, m16 = lane & 15;
    const int hOff = h * HDIM;

    __shared__ __align__(16) bf16 Vs[64 * 64];    // V^T tile (baked swizzle)
    __shared__ __align__(16) bf16 Pw[4][16][72];  // per-wave P: [qrow][kcol]

    const int vrow = tid >> 3, vchunk = (tid & 7) * 8;
    const bf16* VtH = fa.VtG + (size_t)hOff * 2048;
    bf16* __restrict__ Opart = fa.op[s];

#pragma unroll
    for (int ti = 0; ti < 2; ++ti) {
        const int qt = ti ? 31 - pr : pr;
        const int qRow = qt * 64 + w * 16 + m16;  // this lane's q-row
        bf16x8 bq[2];
        bq[0] = *(const bf16x8*)&fa.Q[(size_t)qRow * H_DIM + hOff + quad * 8];
        bq[1] = *(const bf16x8*)&fa.Q[(size_t)qRow * H_DIM + hOff + 32 + quad * 8];

        f32x4 oacc[4] = {};   // O^T C-layout: [d-subtile jd]; row=d, col=qrow
        float m_i = -1e30f, l_i = 0.0f;

        for (int kt = s; kt <= qt; kt += NSPLIT) {
            const int k0 = kt * 64;
            const bool diag = (kt == qt);
            __syncthreads();  // prior PV reads of Vs complete
#pragma unroll
            for (int p = 0; p < 2; ++p) {
                int d = vrow + p * 32;
                async16(VtH + (size_t)d * 2048 + k0 + vchunk,
                        &Vs[d * 64 + vchunk]);
            }
            // S^T = K Q^T
            f32x4 sacc[4] = {};
#pragma unroll
            for (int ks = 0; ks < 2; ++ks)
#pragma unroll
                for (int j = 0; j < 4; ++j) {
                    bf16x8 ak = *(const bf16x8*)
                        &fa.K[(size_t)(k0 + j * 16 + m16) * H_DIM + hOff +
                              ks * 32 + quad * 8];
                    sacc[j] = mfma16(ak, bq[ks], sacc[j]);
                }
            // online softmax: each lane owns q-row m16
            float sv[4][4];
            float mx = -1e30f;
#pragma unroll
            for (int j = 0; j < 4; ++j)
#pragma unroll
                for (int rr = 0; rr < 4; ++rr) {
                    float sc = sacc[j][rr] * 0.125f;
                    int kcol = k0 + j * 16 + quad * 4 + rr;
                    if (diag && kcol > qRow) sc = -1e30f;
                    sv[j][rr] = sc;
                    mx = fmaxf(mx, sc);
                }
            mx = fmaxf(mx, __shfl_xor(mx, 16));
            mx = fmaxf(mx, __shfl_xor(mx, 32));
            float mnew = fmaxf(m_i, mx);
            float alpha = __expf(m_i - mnew);
            m_i = mnew;
            float ls = 0.0f;
#pragma unroll
            for (int j = 0; j < 4; ++j) {
                bf16x4 pk;
#pragma unroll
                for (int rr = 0; rr < 4; ++rr) {
                    float p = __expf(sv[j][rr] - mnew);
                    ls += p;
                    pk[rr] = (bf16)p;
                }
                *(bf16x4*)&Pw[w][m16][j * 16 + quad * 4] = pk;
            }
            ls += __shfl_xor(ls, 16);
            ls += __shfl_xor(ls, 32);
            l_i = l_i * alpha + ls;
#pragma unroll
            for (int jd = 0; jd < 4; ++jd)
#pragma unroll
                for (int rr = 0; rr < 4; ++rr) oacc[jd][rr] *= alpha;
            asm volatile("s_waitcnt vmcnt(0)" ::: "memory");
            __syncthreads();  // V staged; Pw ordered by barrier's lgkm drain
            // O^T += V^T P^T
#pragma unroll
            for (int ks = 0; ks < 2; ++ks) {
                bf16x8 bp = *(const bf16x8*)&Pw[w][m16][ks * 32 + quad * 8];
#pragma unroll
                for (int jd = 0; jd < 4; ++jd) {
                    int d = jd * 16 + m16;
                    bf16x8 av = *(const bf16x8*)
                        &Vs[d * 64 + (((ks * 4 + quad) ^ (d & 7)) << 3)];
                    oacc[jd] = mfma16(av, bp, oacc[jd]);
                }
            }
        }
#pragma unroll
        for (int jd = 0; jd < 4; ++jd) {
            bf16x4 o4;
#pragma unroll
            for (int rr = 0; rr < 4; ++rr) o4[rr] = (bf16)oacc[jd][rr];
            *(bf16x4*)&Opart[(size_t)qRow * 1024 + hOff + jd * 16 + quad * 4] = o4;
        }
        if (quad == 0) {
            float* p = fa.ml + ((size_t)(s * 2048 + qRow) * 16 + h) * 2;
            p[0] = m_i;
            p[1] = l_i;
        }
    }
}

// ---------------------------------------------------------------------------
// Combine the split partials: one wave per (row, head), lane = d.
// ---------------------------------------------------------------------------
struct CombArgs {
    const bf16* op[NSPLIT];
    const float* ml;
    bf16* ctx;
};
__global__ __launch_bounds__(256) void combine_kernel(CombArgs ca) {
    const int unit = blockIdx.x * 4 + (threadIdx.x >> 6);
    const int row = unit >> 4, h = unit & 15;
    const int d = threadIdx.x & 63;
    float mv[NSPLIT], lv[NSPLIT], M = -1e30f;
#pragma unroll
    for (int s2 = 0; s2 < NSPLIT; ++s2) {
        const float* p = ca.ml + ((size_t)(s2 * 2048 + row) * 16 + h) * 2;
        mv[s2] = p[0];
        lv[s2] = p[1];
        M = fmaxf(M, mv[s2]);
    }
    float num = 0.0f, den = 0.0f;
#pragma unroll
    for (int s2 = 0; s2 < NSPLIT; ++s2) {
        float e = __expf(mv[s2] - M);
        den += lv[s2] * e;
        num += e * (float)ca.op[s2][(size_t)row * 1024 + h * 64 + d];
    }
    ca.ctx[(size_t)row * 1024 + h * 64 + d] = (bf16)(num / den);
}

// ---------------------------------------------------------------------------
// Orchestration. Inputs/outputs FLOAT32 per the reference.
// ws layout (40 MB, phase-aliased):
//   0..4M    xb -> qb                16..24M  kb16[0..3] (kb16[3]=proj key)
//   4..16M   g3[0..2] -> Opart s0-2  24..32M  vT16[0..3] (vT16[3]=proj val)
//   16..20M  kb16[0,1] (dead) -> Opart s3
//   20..22M  kb16[2]   (dead) -> ml (1M) + Sbuf (24K @ +1.5M)
//   32..36M  kbuf -> ctx
//   36..40M  VtG (written by gemm2 z=2 epilogue; no vbuf needed)
//   projg aliases 4..8M after combine.
// ---------------------------------------------------------------------------
extern "C" void kernel_launch(void* const* d_in, const int* in_sizes, int n_in,
                              void* d_out, int out_size, void* d_ws,
                              size_t ws_size, hipStream_t stream) {
    const float* x = (const float*)d_in[0];
    const float* keysF[4] = {(const float*)d_in[1], (const float*)d_in[3],
                             (const float*)d_in[5], (const float*)d_in[7]};
    const float* valsF[4] = {(const float*)d_in[2], (const float*)d_in[4],
                             (const float*)d_in[6], (const float*)d_in[8]};
    float* out = (float*)d_out;

    char* ws = (char*)d_ws;
    bf16* xb = (bf16*)(ws);
    bf16* g3[3];
    for (int i = 0; i < 3; ++i) g3[i] = (bf16*)(ws + (4ull << 20) + (size_t)i * (4ull << 20));
    bf16* kb16[4], *vT16[4];
    for (int i = 0; i < 4; ++i) {
        kb16[i] = (bf16*)(ws + (16ull << 20) + (size_t)i * (2ull << 20));
        vT16[i] = (bf16*)(ws + (24ull << 20) + (size_t)i * (2ull << 20));
    }
    bf16* qb    = (bf16*)(ws);
    bf16* kbuf  = (bf16*)(ws + (32ull << 20));
    float* mlbuf = (float*)(ws + (20ull << 20));
    float* Sbuf = (float*)(ws + (20ull << 20) + (1536ull << 10));
    bf16* VtG   = (bf16*)(ws + (36ull << 20));
    bf16* ctx   = (bf16*)(ws + (32ull << 20));
    bf16* projg = (bf16*)(ws + (4ull << 20));

    bf16* opart[NSPLIT];
    for (int i = 0; i < NSPLIT; ++i)
        opart[i] = (bf16*)(ws + (4ull << 20) + (size_t)i * (4ull << 20));

    // 1. convert x + 4 key matrices to bf16
    ConvArgs cva;
    cva.src[0] = x;             cva.dst[0] = xb;
    cva.src[1] = x + (1 << 20); cva.dst[1] = xb + (1 << 20);
    for (int i = 0; i < 4; ++i) { cva.src[2 + i] = keysF[i]; cva.dst[2 + i] = kb16[i]; }
    convert6<<<dim3(1024, 6), 256, 0, stream>>>(cva);

    // 2. convert + transpose the 4 val matrices
    TcArgs ta;
    for (int i = 0; i < 4; ++i) { ta.src[i] = valsF[i]; ta.dst[i] = vT16[i]; }
    transpose_cvt<<<dim3(32, 32, 4), dim3(32, 8), 0, stream>>>(ta);

    // 3. batched QKV: g = gelu(x @ key^T)
    GemmArgs<1, bf16> g1;
    for (int z = 0; z < 3; ++z) {
        g1.A[z] = xb; g1.B[z] = kb16[z]; g1.C[z] = g3[z];
        g1.S[z] = nullptr; g1.Ct[z] = nullptr;
    }
    gemm_bt<1, bf16><<<dim3(16, 16, 3), 256, 0, stream>>>(g1);

    // 4. row scales only (g untouched)
    ScaleArgs sa;
    for (int z = 0; z < 3; ++z) { sa.G[z] = g3[z]; sa.S[z] = Sbuf + z * 2048; }
    rowscale_kernel<<<dim3(2048, 3), 256, 0, stream>>>(sa);

    // 5. batched: q,k row-major; V written directly transposed+swizzled (VtG)
    GemmArgs<2, bf16> g2;
    bf16* qkv[3] = {qb, kbuf, qb /*unused for z=2*/};
    for (int z = 0; z < 3; ++z) {
        g2.A[z] = g3[z]; g2.B[z] = vT16[z]; g2.C[z] = qkv[z];
        g2.S[z] = Sbuf + z * 2048;
        g2.Ct[z] = (z == 2) ? VtG : nullptr;
    }
    gemm_bt<2, bf16><<<dim3(16, 16, 3), 256, 0, stream>>>(g2);

    // 6. flash attention (S^T form, XCD-aware 1-D grid, 4-way split)
    FlashArgs fla;
    fla.Q = qb; fla.K = kbuf; fla.VtG = VtG; fla.ml = mlbuf;
    for (int i = 0; i < NSPLIT; ++i) fla.op[i] = opart[i];
    flash_kernel<<<dim3(1024), 256, 0, stream>>>(fla);

    // 7. combine split partials -> ctx
    CombArgs cba;
    for (int i = 0; i < NSPLIT; ++i) cba.op[i] = opart[i];
    cba.ml = mlbuf; cba.ctx = ctx;
    combine_kernel<<<dim3(8192), 256, 0, stream>>>(cba);

    // 8-10. output projection pattention (512-thread GEMMs, 8 waves/CU)
    GemmArgs<1, bf16> p1;
    for (int z = 0; z < 3; ++z) {
        p1.A[z] = ctx; p1.B[z] = kb16[3]; p1.C[z] = projg;
        p1.S[z] = nullptr; p1.Ct[z] = nullptr;
    }
    gemm_bt512<1, bf16><<<dim3(16, 16, 1), 512, 0, stream>>>(p1);

    ScaleArgs sp;
    for (int z = 0; z < 3; ++z) { sp.G[z] = projg; sp.S[z] = Sbuf; }
    rowscale_kernel<<<dim3(2048, 1), 256, 0, stream>>>(sp);

    GemmArgs<2, float> p2;
    for (int z = 0; z < 3; ++z) {
        p2.A[z] = projg; p2.B[z] = vT16[3]; p2.C[z] = out;
        p2.S[z] = Sbuf; p2.Ct[z] = nullptr;
    }
    gemm_bt512<2, float><<<dim3(16, 16, 1), 512, 0, stream>>>(p2);
}